// Round 1
// baseline (594.615 us; speedup 1.0000x reference)
//
#include <hip/hip_runtime.h>
#include <math.h>

#define NSITE 2048

// flat output offsets (floats), reference return order
#define OFF_XOUT 0
#define OFF_AGR  (NSITE*64)                // 131072
#define OFF_POSE (OFF_AGR + NSITE*64)      // 262144
#define OFF_XP   (OFF_POSE + NSITE*128)    // 524288

// ws layout (float indices):
//   [0,262144)        h fp32 [2048][128]           (exact path)
//   [262144,266240)   meta float2 [2048]           (Sa, cnt)
//   [266240,397312)   h_hi bf16 [2048][128] (as shorts)
//   [397312,528384)   h_lo bf16
//   [528384,659456)   h_zz bf16 (3rd split term)
//   [659456]          worklist counter (uint)
//   [659457,790529)   worklist entries (int: site<<6 | co), worst case 131072
// total ~3.0 MB
#define WS_META_OFF (NSITE*128)
#define WS_HHI_OFF  266240
#define WS_HLO_OFF  397312
#define WS_HZZ_OFF  528384
#define WS_CNT_OFF  659456
#define WS_LST_OFF  659457

typedef __attribute__((ext_vector_type(8))) short bf16x8;
typedef __attribute__((ext_vector_type(4))) float f32x4;
typedef unsigned char uchar;

__device__ __forceinline__ short f2bf(float f) {
    union { float f; unsigned u; } c; c.f = f;
    const unsigned r = c.u + 0x7FFF + ((c.u >> 16) & 1);   // RNE
    return (short)(r >> 16);
}
__device__ __forceinline__ float bf2f(short h) {
    union { unsigned u; float f; } c; c.u = ((unsigned)(unsigned short)h) << 16;
    return c.f;
}
__device__ __forceinline__ void f2bf_split3(float f, short* hi, short* lo, short* ll) {
    *hi = f2bf(f);
    const float r = f - bf2f(*hi);
    *lo = f2bf(r);
    *ll = f2bf(r - bf2f(*lo));
}

// guarded normalize matching ref semantics: out_c = (mu_c==0) ? 0 : mu_c/||mu||
__device__ __forceinline__ void norm2_guard(float x, float y, float* ox, float* oy) {
    const float n2  = x*x + y*y;
    const float inv = (n2 > 0.f) ? rsqrtf(n2) : 0.f;
    *ox = x*inv; *oy = y*inv;
}
// variant tracking min ||mu||^2 for the margin flag
__device__ __forceinline__ void norm2_guard_m(float x, float y, float* ox, float* oy, float* minr2) {
    const float n2  = x*x + y*y;
    *minr2 = fminf(*minr2, n2);
    const float inv = (n2 > 0.f) ? rsqrtf(n2) : 0.f;
    *ox = x*inv; *oy = y*inv;
}

// ---------------------------------------------------------------------------
// Kernel A: one wave per site (R7-validated pipeline, arithmetic untouched).
// Adds: store h also as a 3-way bf16 split for the MFMA pass A-fragments.
// Also zeroes the fixup worklist counter (runs before capsB_m on-stream).
// ---------------------------------------------------------------------------
__global__ __launch_bounds__(256) void capsA(
    const float* __restrict__ x, const float* __restrict__ a,
    const float* __restrict__ pose,
    const float* __restrict__ tg1, const float* __restrict__ lin_w,
    const float* __restrict__ lin_b, float* __restrict__ out,
    float* __restrict__ ws)
{
    if (blockIdx.x == 0 && threadIdx.x == 0)
        ((unsigned*)(ws + WS_CNT_OFF))[0] = 0u;

    const int wave = threadIdx.x >> 6, lane = threadIdx.x & 63;
    const int s  = blockIdx.x*4 + wave;
    const int b  = s >> 8, hp = (s >> 4) & 15, wp = s & 15;
    const int ci = lane & 31, p0 = lane >> 5;           // p0 in {0,1}

    __shared__ float stp[4][4][64];
    __shared__ float xps[4][32];

    const int base = ((b*32 + 2*hp)*32 + 2*wp)*32 + ci;
    const int i0 = base + p0*32;
    const int i1 = base + 1024 + p0*32;
    const float2 pe0 = ((const float2*)pose)[i0];
    const float2 pe1 = ((const float2*)pose)[i1];
    const float  x0  = x[i0], x1 = x[i1];
    const float  a0  = a[i0], a1 = a[i1];

    // pose pooling sum in exact reference order ((p0+p1)+p2)+p3
    const float o0x = __shfl_xor(pe0.x, 32, 64);
    const float o0y = __shfl_xor(pe0.y, 32, 64);
    const float o1x = __shfl_xor(pe1.x, 32, 64);
    const float o1y = __shfl_xor(pe1.y, 32, 64);
    const bool first = (p0 == 0);
    const float A0x = first ? pe0.x : o0x,  A1x = first ? o0x : pe0.x;
    const float A2x = first ? pe1.x : o1x,  A3x = first ? o1x : pe1.x;
    const float A0y = first ? pe0.y : o0y,  A1y = first ? o0y : pe0.y;
    const float A2y = first ? pe1.y : o1y,  A3y = first ? o1y : pe1.y;
    float mx = ((A0x + A1x) + A2x) + A3x;
    float my = ((A0y + A1y) + A2y) + A3y;

    float xm = fmaxf(x0, x1);
    xm = fmaxf(xm, __shfl_xor(xm, 32, 64));
    float sa  = a0 + a1;
    float cnt = (a0 != 0.f ? 1.f : 0.f) + (a1 != 0.f ? 1.f : 0.f);
    sa  += __shfl_xor(sa,  32, 64);
    cnt += __shfl_xor(cnt, 32, 64);
    #pragma unroll
    for (int m = 1; m <= 16; m <<= 1) {
        sa  += __shfl_xor(sa,  m, 64);
        cnt += __shfl_xor(cnt, m, 64);
    }
    if (lane == 0) ((float2*)(ws + WS_META_OFF))[s] = make_float2(sa, cnt);
    if (p0 == 0) {
        out[OFF_XP + s*32 + ci] = xm;
        xps[wave][ci] = xm;
    }

    {
        const float n   = sqrtf(mx*mx + my*my);
        const float den = n + (n == 0.f ? 1.f : 0.f);
        mx /= den; my /= den;
    }
    {
        const float ww_ = (float)p0 - 0.5f;
        const float t0x = -0.5f*mx + my*ww_;
        const float t0y =  0.5f*my + mx*ww_;
        const float t1x =  0.5f*mx + my*ww_;
        const float t1y = -0.5f*my + mx*ww_;
        ((float2*)stp[wave][p0    ])[ci] = make_float2(t0x, t0y);
        ((float2*)stp[wave][p0 + 2])[ci] = make_float2(t1x, t1y);
    }
    __syncthreads();

    {
        const float4* w4 = (const float4*)(tg1 + ci*64);
        const float4* r0 = (const float4*)stp[wave][p0];
        const float4* r1 = (const float4*)stp[wave][p0 + 2];
        float h0 = 0.f, h1 = 0.f;
        #pragma unroll
        for (int k = 0; k < 16; ++k) {
            const float4 wv = w4[k], u = r0[k], v = r1[k];
            h0 += wv.x*u.x + wv.y*u.y + wv.z*u.z + wv.w*u.w;
            h1 += wv.x*v.x + wv.y*v.y + wv.z*v.z + wv.w*v.w;
        }
        ws[s*128 + p0*32 + ci]       = h0;
        ws[s*128 + (p0 + 2)*32 + ci] = h1;
        // bf16 3-way split for the MFMA pass
        short* hhi = (short*)(ws + WS_HHI_OFF);
        short* hlo = (short*)(ws + WS_HLO_OFF);
        short* hzz = (short*)(ws + WS_HZZ_OFF);
        short h0h, h0l, h0z, h1h, h1l, h1z;
        f2bf_split3(h0, &h0h, &h0l, &h0z);
        f2bf_split3(h1, &h1h, &h1l, &h1z);
        const int e0 = s*128 + p0*32 + ci;
        const int e1 = s*128 + (p0 + 2)*32 + ci;
        hhi[e0] = h0h; hhi[e1] = h1h;
        hlo[e0] = h0l; hlo[e1] = h1l;
        hzz[e0] = h0z; hzz[e1] = h1z;
    }

    {
        float acc = lin_b[lane];
        const float4* lw = (const float4*)(lin_w + lane*32);
        const float4* xv = (const float4*)xps[wave];
        #pragma unroll
        for (int k = 0; k < 8; ++k) {
            const float4 wv = lw[k], u = xv[k];
            acc += wv.x*u.x + wv.y*u.y + wv.z*u.z + wv.w*u.w;
        }
        out[OFF_XOUT + s*64 + lane] = acc;
    }
}

// ---------------------------------------------------------------------------
// Pass 1: MFMA theta (A 3-way x B 3-way, 6 terms kept per half) + moment
// routing for ALL pairs, tracking min ||mu||^2; pairs with ||mu|| < 0.05*Sa
// are APPENDED TO A COMPACT WORKLIST (atomic counter) instead of a flag
// array — the fixup pass then only touches real work.
// Wave tile: M=16 (4 sites x 4 p) x N=32 (one co), K=32.
// ---------------------------------------------------------------------------
__global__ __launch_bounds__(256) void capsB_m(
    const float* __restrict__ a, const float* __restrict__ pose,
    const float* __restrict__ tg2, float* __restrict__ ws,
    const float* __restrict__ alpha, const float* __restrict__ beta,
    float* __restrict__ out)
{
    const int co   = blockIdx.x;
    const int tid  = threadIdx.x;
    const int wave = tid >> 6, lane = tid & 63;
    const int q    = lane >> 4;
    const int n    = lane & 15;

    // B fragments, 3-way split (once per wave)
    bf16x8 b0h, b0l, b0z, b1h, b1l, b1z;
    {
        const float* r0 = tg2 + (co*32 + n)*32 + q*8;
        const float* r1 = r0 + 512;
        #pragma unroll
        for (int j = 0; j < 8; ++j) {
            short h, l, z;
            f2bf_split3(r0[j], &h, &l, &z); b0h[j] = h; b0l[j] = l; b0z[j] = z;
            f2bf_split3(r1[j], &h, &l, &z); b1h[j] = h; b1l[j] = l; b1z[j] = z;
        }
    }
    const short* hhi = (const short*)(ws + WS_HHI_OFF);
    const short* hlo = (const short*)(ws + WS_HLO_OFF);
    const short* hzz = (const short*)(ws + WS_HZZ_OFF);
    unsigned* wl_cnt = (unsigned*)(ws + WS_CNT_OFF);
    int*      wl_lst = (int*)(ws + WS_LST_OFF);
    const float alp = alpha[0];
    const float bet = beta[0] - 1.0f;
    const float2* ws_meta = (const float2*)(ws + WS_META_OFF);

    #pragma unroll
    for (int it = 0; it < 4; ++it) {
        const int s0 = (((blockIdx.y*4 + wave)*4) + it)*4;

        const int aoff = (s0 + (n >> 2))*128 + (n & 3)*32 + q*8;
        const bf16x8 ah = *(const bf16x8*)(hhi + aoff);
        const bf16x8 al = *(const bf16x8*)(hlo + aoff);
        const bf16x8 az = *(const bf16x8*)(hzz + aoff);

        f32x4 c0 = {0.f, 0.f, 0.f, 0.f};
        f32x4 c1 = {0.f, 0.f, 0.f, 0.f};
        // smallest terms first
        c0 = __builtin_amdgcn_mfma_f32_16x16x32_bf16(az, b0h, c0, 0, 0, 0);
        c0 = __builtin_amdgcn_mfma_f32_16x16x32_bf16(ah, b0z, c0, 0, 0, 0);
        c0 = __builtin_amdgcn_mfma_f32_16x16x32_bf16(al, b0l, c0, 0, 0, 0);
        c0 = __builtin_amdgcn_mfma_f32_16x16x32_bf16(al, b0h, c0, 0, 0, 0);
        c0 = __builtin_amdgcn_mfma_f32_16x16x32_bf16(ah, b0l, c0, 0, 0, 0);
        c0 = __builtin_amdgcn_mfma_f32_16x16x32_bf16(ah, b0h, c0, 0, 0, 0);
        c1 = __builtin_amdgcn_mfma_f32_16x16x32_bf16(az, b1h, c1, 0, 0, 0);
        c1 = __builtin_amdgcn_mfma_f32_16x16x32_bf16(ah, b1z, c1, 0, 0, 0);
        c1 = __builtin_amdgcn_mfma_f32_16x16x32_bf16(al, b1l, c1, 0, 0, 0);
        c1 = __builtin_amdgcn_mfma_f32_16x16x32_bf16(al, b1h, c1, 0, 0, 0);
        c1 = __builtin_amdgcn_mfma_f32_16x16x32_bf16(ah, b1l, c1, 0, 0, 0);
        c1 = __builtin_amdgcn_mfma_f32_16x16x32_bf16(ah, b1h, c1, 0, 0, 0);

        const int site = s0 + q;
        const int b    = site >> 8, hpi = (site >> 4) & 15, wpi = site & 15;
        const int base = ((b*32 + 2*hpi)*32 + 2*wpi)*32;

        float Sx = 0.f, Sy = 0.f, Sxx = 0.f, Sxy = 0.f, Syy = 0.f;
        #pragma unroll
        for (int p = 0; p < 4; ++p) {
            const int idx0 = base + (p >> 1)*1024 + (p & 1)*32 + n;
            const int idx1 = idx0 + 16;
            const float2 pe0 = ((const float2*)pose)[idx0];
            const float2 pe1 = ((const float2*)pose)[idx1];
            const float  a0  = a[idx0];
            const float  a1  = a[idx1];
            float s0n, c0n, s1n, c1n;
            __sincosf(c0[p], &s0n, &c0n);
            __sincosf(c1[p], &s1n, &c1n);
            const float v0x = pe0.x*c0n - pe0.y*s0n;
            const float v0y = pe0.y*c0n + pe0.x*s0n;
            const float v1x = pe1.x*c1n - pe1.y*s1n;
            const float v1y = pe1.y*c1n + pe1.x*s1n;
            const float a0x = a0*v0x, a0y = a0*v0y;
            const float a1x = a1*v1x, a1y = a1*v1y;
            Sx  += a0x + a1x;
            Sy  += a0y + a1y;
            Sxx += a0x*v0x + a1x*v1x;
            Sxy += a0x*v0y + a1x*v1y;
            Syy += a0y*v0y + a1y*v1y;
        }
        #pragma unroll
        for (int m = 1; m <= 8; m <<= 1) {
            Sx  += __shfl_xor(Sx,  m, 64);
            Sy  += __shfl_xor(Sy,  m, 64);
            Sxx += __shfl_xor(Sxx, m, 64);
            Sxy += __shfl_xor(Sxy, m, 64);
            Syy += __shfl_xor(Syy, m, 64);
        }

        float minr2 = 3.4e38f;
        float px, py;
        norm2_guard_m(Sx, Sy, &px, &py, &minr2);
        float qx = px, qy = py;
        #pragma unroll
        for (int it2 = 0; it2 < 3; ++it2) {
            qx = px; qy = py;
            const float mx = Sx + px*Sxx + py*Sxy;
            const float my = Sy + px*Sxy + py*Syy;
            norm2_guard_m(mx, my, &px, &py, &minr2);
        }
        const float2 meta = ws_meta[site];
        const float nd_sum = 0.25f*(meta.x + (px + qx)*Sx + (py + qy)*Sy
                           + px*qx*Sxx + (px*qy + py*qx)*Sxy + py*qy*Syy);
        const float wsum = meta.y;
        const float msk  = (wsum != 0.f) ? 1.f : 0.f;
        const float nd   = nd_sum / (wsum + (1.f - msk)) * msk;
        const float z    = alp*nd + bet;
        const float agr  = msk / (1.f + __expf(-z));
        // margin flag: ||mu|| < 0.05 * Sa
        const int fl = (minr2 < 2.5e-3f*(meta.x*meta.x)) ? 1 : 0;

        if (n == 0) {
            out[OFF_AGR  + site*64  + co]       = agr;
            out[OFF_POSE + site*128 + co*2]     = px;
            out[OFF_POSE + site*128 + co*2 + 1] = py;
            if (fl) {
                const unsigned k = atomicAdd(wl_cnt, 1u);
                wl_lst[k] = (site << 6) | co;
            }
        }
    }
}

// ---------------------------------------------------------------------------
// Pass 2: exact fixup, worklist-driven. 32 workgroups grid-stride the
// compact list of flagged (site,co) pairs; each 32-lane half-wave runs the
// R13-validated routing VERBATIM (bit-identical to the 0.0039 pass) and
// overwrites. Uniform early-exit when the list is empty.
// ---------------------------------------------------------------------------
__global__ __launch_bounds__(256) void capsB_fix(
    const float* __restrict__ a, const float* __restrict__ pose,
    const float* __restrict__ tg2, const float* __restrict__ ws,
    const float* __restrict__ alpha, const float* __restrict__ beta,
    float* __restrict__ out)
{
    const unsigned cnt = *(const unsigned*)(ws + WS_CNT_OFF);
    if (cnt == 0) return;

    const int tid  = threadIdx.x;
    const int wave = tid >> 6, lane = tid & 63;
    const int ci   = lane & 31;

    const float alp = alpha[0];
    const float bet = beta[0] - 1.0f;
    const float2* ws_meta = (const float2*)(ws + WS_META_OFF);
    const int* list = (const int*)(ws + WS_LST_OFF);
    const unsigned stride = gridDim.x * 8u;   // half-waves in the grid

    for (unsigned e = (blockIdx.x*4 + wave)*2 + (lane >> 5); e < cnt; e += stride) {
        const int ent = list[e];
        const int s   = ent >> 6;
        const int co  = ent & 63;

        float4 r[8];
        {
            const float4* rp = (const float4*)(tg2 + (co*32 + ci)*32);
            #pragma unroll
            for (int k = 0; k < 8; ++k) r[k] = rp[k];
        }

        const float4* h4 = (const float4*)(ws + s*128);
        float th0 = 0.f, th1 = 0.f, th2 = 0.f, th3 = 0.f;
        #pragma unroll
        for (int k = 0; k < 8; ++k) {
            const float4 rk = r[k];
            const float4 ha = h4[k];
            const float4 hb = h4[8  + k];
            const float4 hc = h4[16 + k];
            const float4 hd = h4[24 + k];
            th0 += rk.x*ha.x + rk.y*ha.y + rk.z*ha.z + rk.w*ha.w;
            th1 += rk.x*hb.x + rk.y*hb.y + rk.z*hb.z + rk.w*hb.w;
            th2 += rk.x*hc.x + rk.y*hc.y + rk.z*hc.z + rk.w*hc.w;
            th3 += rk.x*hd.x + rk.y*hd.y + rk.z*hd.z + rk.w*hd.w;
        }
        const float th[4] = {th0, th1, th2, th3};

        const int b   = s >> 8, hpi = (s >> 4) & 15, wpi = s & 15;
        const int base = ((b*32 + 2*hpi)*32 + 2*wpi)*32 + ci;

        float Sx = 0.f, Sy = 0.f, Sxx = 0.f, Sxy = 0.f, Syy = 0.f;
        #pragma unroll
        for (int p = 0; p < 4; ++p) {
            const int idx = base + (p >> 1)*1024 + (p & 1)*32;
            const float2 pe = ((const float2*)pose)[idx];
            const float  av = a[idx];
            float sn, cs;
            __sincosf(th[p], &sn, &cs);
            const float vx = pe.x*cs - pe.y*sn;
            const float vy = pe.y*cs + pe.x*sn;
            const float ax = av*vx, ay = av*vy;
            Sx += ax; Sy += ay;
            Sxx += ax*vx; Sxy += ax*vy; Syy += ay*vy;
        }
        #pragma unroll
        for (int m = 1; m <= 16; m <<= 1) {
            Sx  += __shfl_xor(Sx,  m, 64);
            Sy  += __shfl_xor(Sy,  m, 64);
            Sxx += __shfl_xor(Sxx, m, 64);
            Sxy += __shfl_xor(Sxy, m, 64);
            Syy += __shfl_xor(Syy, m, 64);
        }

        float px, py;
        norm2_guard(Sx, Sy, &px, &py);
        float qx = px, qy = py;
        #pragma unroll
        for (int it = 0; it < 3; ++it) {
            qx = px; qy = py;
            const float mx = Sx + px*Sxx + py*Sxy;
            const float my = Sy + px*Sxy + py*Syy;
            norm2_guard(mx, my, &px, &py);
        }
        const float2 meta = ws_meta[s];
        const float nd_sum = 0.25f*(meta.x + (px + qx)*Sx + (py + qy)*Sy
                           + px*qx*Sxx + (px*qy + py*qx)*Sxy + py*qy*Syy);
        const float wsum = meta.y;
        const float msk  = (wsum != 0.f) ? 1.f : 0.f;
        const float nd   = nd_sum / (wsum + (1.f - msk)) * msk;
        const float z    = alp*nd + bet;
        const float agr  = msk / (1.f + __expf(-z));

        if ((lane & 31) == 0) {
            out[OFF_AGR  + s*64  + co]       = agr;
            out[OFF_POSE + s*128 + co*2]     = px;
            out[OFF_POSE + s*128 + co*2 + 1] = py;
        }
    }
}

extern "C" void kernel_launch(void* const* d_in, const int* in_sizes, int n_in,
                              void* d_out, int out_size, void* d_ws, size_t ws_size,
                              hipStream_t stream) {
    const float* x     = (const float*)d_in[0];
    const float* a     = (const float*)d_in[1];
    const float* pose  = (const float*)d_in[2];
    const float* alpha = (const float*)d_in[3];
    const float* beta  = (const float*)d_in[4];
    const float* lin_w = (const float*)d_in[5];
    const float* lin_b = (const float*)d_in[6];
    const float* tg1   = (const float*)d_in[7];
    const float* tg2   = (const float*)d_in[8];
    float* out = (float*)d_out;
    float* ws  = (float*)d_ws;   // ~3.0 MB used

    capsA<<<NSITE/4, 256, 0, stream>>>(x, a, pose, tg1, lin_w, lin_b, out, ws);
    capsB_m<<<dim3(64, 32), 256, 0, stream>>>(a, pose, tg2, ws, alpha, beta, out);
    capsB_fix<<<dim3(32), 256, 0, stream>>>(a, pose, tg2, ws, alpha, beta, out);
}

// Round 2
// 145.879 us; speedup vs baseline: 4.0761x; 4.0761x over previous
//
#include <hip/hip_runtime.h>
#include <math.h>

#define NSITE 2048

// flat output offsets (floats), reference return order
#define OFF_XOUT 0
#define OFF_AGR  (NSITE*64)                // 131072
#define OFF_POSE (OFF_AGR + NSITE*64)      // 262144
#define OFF_XP   (OFF_POSE + NSITE*128)    // 524288

// ws layout (float indices):
//   [0,262144)        h fp32 [2048][128]           (exact path)
//   [262144,266240)   meta float2 [2048]           (Sa, cnt)
//   [266240,397312)   h_hi bf16 [2048][128] (as shorts)
//   [397312,528384)   h_lo bf16
//   [528384,659456)   h_zz bf16 (3rd split term)
//   [659456,692224)   flags uchar [2048*64]        (131072 bytes)
//   [692224]          worklist counter (uint)
//   [692225,823297)   worklist entries (int: site<<6 | co)
// total ~3.3 MB
#define WS_META_OFF (NSITE*128)
#define WS_HHI_OFF  266240
#define WS_HLO_OFF  397312
#define WS_HZZ_OFF  528384
#define WS_FLG_OFF  659456
#define WS_CNT_OFF  692224
#define WS_LST_OFF  692225

typedef __attribute__((ext_vector_type(8))) short bf16x8;
typedef __attribute__((ext_vector_type(4))) float f32x4;
typedef unsigned char uchar;

__device__ __forceinline__ short f2bf(float f) {
    union { float f; unsigned u; } c; c.f = f;
    const unsigned r = c.u + 0x7FFF + ((c.u >> 16) & 1);   // RNE
    return (short)(r >> 16);
}
__device__ __forceinline__ float bf2f(short h) {
    union { unsigned u; float f; } c; c.u = ((unsigned)(unsigned short)h) << 16;
    return c.f;
}
__device__ __forceinline__ void f2bf_split3(float f, short* hi, short* lo, short* ll) {
    *hi = f2bf(f);
    const float r = f - bf2f(*hi);
    *lo = f2bf(r);
    *ll = f2bf(r - bf2f(*lo));
}

// guarded normalize matching ref semantics: out_c = (mu_c==0) ? 0 : mu_c/||mu||
__device__ __forceinline__ void norm2_guard(float x, float y, float* ox, float* oy) {
    const float n2  = x*x + y*y;
    const float inv = (n2 > 0.f) ? rsqrtf(n2) : 0.f;
    *ox = x*inv; *oy = y*inv;
}
// variant tracking min ||mu||^2 for the margin flag
__device__ __forceinline__ void norm2_guard_m(float x, float y, float* ox, float* oy, float* minr2) {
    const float n2  = x*x + y*y;
    *minr2 = fminf(*minr2, n2);
    const float inv = (n2 > 0.f) ? rsqrtf(n2) : 0.f;
    *ox = x*inv; *oy = y*inv;
}

// ---------------------------------------------------------------------------
// Kernel A: one wave per site (R7-validated pipeline, arithmetic untouched).
// Adds: store h also as a 3-way bf16 split for the MFMA pass A-fragments.
// Also zeroes the fixup worklist counter (runs before capsC on-stream).
// ---------------------------------------------------------------------------
__global__ __launch_bounds__(256) void capsA(
    const float* __restrict__ x, const float* __restrict__ a,
    const float* __restrict__ pose,
    const float* __restrict__ tg1, const float* __restrict__ lin_w,
    const float* __restrict__ lin_b, float* __restrict__ out,
    float* __restrict__ ws)
{
    if (blockIdx.x == 0 && threadIdx.x == 0)
        ((unsigned*)(ws + WS_CNT_OFF))[0] = 0u;

    const int wave = threadIdx.x >> 6, lane = threadIdx.x & 63;
    const int s  = blockIdx.x*4 + wave;
    const int b  = s >> 8, hp = (s >> 4) & 15, wp = s & 15;
    const int ci = lane & 31, p0 = lane >> 5;           // p0 in {0,1}

    __shared__ float stp[4][4][64];
    __shared__ float xps[4][32];

    const int base = ((b*32 + 2*hp)*32 + 2*wp)*32 + ci;
    const int i0 = base + p0*32;
    const int i1 = base + 1024 + p0*32;
    const float2 pe0 = ((const float2*)pose)[i0];
    const float2 pe1 = ((const float2*)pose)[i1];
    const float  x0  = x[i0], x1 = x[i1];
    const float  a0  = a[i0], a1 = a[i1];

    // pose pooling sum in exact reference order ((p0+p1)+p2)+p3
    const float o0x = __shfl_xor(pe0.x, 32, 64);
    const float o0y = __shfl_xor(pe0.y, 32, 64);
    const float o1x = __shfl_xor(pe1.x, 32, 64);
    const float o1y = __shfl_xor(pe1.y, 32, 64);
    const bool first = (p0 == 0);
    const float A0x = first ? pe0.x : o0x,  A1x = first ? o0x : pe0.x;
    const float A2x = first ? pe1.x : o1x,  A3x = first ? o1x : pe1.x;
    const float A0y = first ? pe0.y : o0y,  A1y = first ? o0y : pe0.y;
    const float A2y = first ? pe1.y : o1y,  A3y = first ? o1y : pe1.y;
    float mx = ((A0x + A1x) + A2x) + A3x;
    float my = ((A0y + A1y) + A2y) + A3y;

    float xm = fmaxf(x0, x1);
    xm = fmaxf(xm, __shfl_xor(xm, 32, 64));
    float sa  = a0 + a1;
    float cnt = (a0 != 0.f ? 1.f : 0.f) + (a1 != 0.f ? 1.f : 0.f);
    sa  += __shfl_xor(sa,  32, 64);
    cnt += __shfl_xor(cnt, 32, 64);
    #pragma unroll
    for (int m = 1; m <= 16; m <<= 1) {
        sa  += __shfl_xor(sa,  m, 64);
        cnt += __shfl_xor(cnt, m, 64);
    }
    if (lane == 0) ((float2*)(ws + WS_META_OFF))[s] = make_float2(sa, cnt);
    if (p0 == 0) {
        out[OFF_XP + s*32 + ci] = xm;
        xps[wave][ci] = xm;
    }

    {
        const float n   = sqrtf(mx*mx + my*my);
        const float den = n + (n == 0.f ? 1.f : 0.f);
        mx /= den; my /= den;
    }
    {
        const float ww_ = (float)p0 - 0.5f;
        const float t0x = -0.5f*mx + my*ww_;
        const float t0y =  0.5f*my + mx*ww_;
        const float t1x =  0.5f*mx + my*ww_;
        const float t1y = -0.5f*my + mx*ww_;
        ((float2*)stp[wave][p0    ])[ci] = make_float2(t0x, t0y);
        ((float2*)stp[wave][p0 + 2])[ci] = make_float2(t1x, t1y);
    }
    __syncthreads();

    {
        const float4* w4 = (const float4*)(tg1 + ci*64);
        const float4* r0 = (const float4*)stp[wave][p0];
        const float4* r1 = (const float4*)stp[wave][p0 + 2];
        float h0 = 0.f, h1 = 0.f;
        #pragma unroll
        for (int k = 0; k < 16; ++k) {
            const float4 wv = w4[k], u = r0[k], v = r1[k];
            h0 += wv.x*u.x + wv.y*u.y + wv.z*u.z + wv.w*u.w;
            h1 += wv.x*v.x + wv.y*v.y + wv.z*v.z + wv.w*v.w;
        }
        ws[s*128 + p0*32 + ci]       = h0;
        ws[s*128 + (p0 + 2)*32 + ci] = h1;
        // bf16 3-way split for the MFMA pass
        short* hhi = (short*)(ws + WS_HHI_OFF);
        short* hlo = (short*)(ws + WS_HLO_OFF);
        short* hzz = (short*)(ws + WS_HZZ_OFF);
        short h0h, h0l, h0z, h1h, h1l, h1z;
        f2bf_split3(h0, &h0h, &h0l, &h0z);
        f2bf_split3(h1, &h1h, &h1l, &h1z);
        const int e0 = s*128 + p0*32 + ci;
        const int e1 = s*128 + (p0 + 2)*32 + ci;
        hhi[e0] = h0h; hhi[e1] = h1h;
        hlo[e0] = h0l; hlo[e1] = h1l;
        hzz[e0] = h0z; hzz[e1] = h1z;
    }

    {
        float acc = lin_b[lane];
        const float4* lw = (const float4*)(lin_w + lane*32);
        const float4* xv = (const float4*)xps[wave];
        #pragma unroll
        for (int k = 0; k < 8; ++k) {
            const float4 wv = lw[k], u = xv[k];
            acc += wv.x*u.x + wv.y*u.y + wv.z*u.z + wv.w*u.w;
        }
        out[OFF_XOUT + s*64 + lane] = acc;
    }
}

// ---------------------------------------------------------------------------
// Pass 1: MFMA theta (A 3-way x B 3-way, 6 terms kept per half) + moment
// routing for ALL pairs, tracking min ||mu||^2; pairs with ||mu|| < 0.05*Sa
// set a FLAG BYTE (contention-free store, no atomics — R1 showed ~15k
// single-address atomicAdds cost ~200us of L2 serialization).
// Wave tile: M=16 (4 sites x 4 p) x N=32 (one co), K=32.
// ---------------------------------------------------------------------------
__global__ __launch_bounds__(256) void capsB_m(
    const float* __restrict__ a, const float* __restrict__ pose,
    const float* __restrict__ tg2, float* __restrict__ ws,
    const float* __restrict__ alpha, const float* __restrict__ beta,
    float* __restrict__ out)
{
    const int co   = blockIdx.x;
    const int tid  = threadIdx.x;
    const int wave = tid >> 6, lane = tid & 63;
    const int q    = lane >> 4;
    const int n    = lane & 15;

    // B fragments, 3-way split (once per wave)
    bf16x8 b0h, b0l, b0z, b1h, b1l, b1z;
    {
        const float* r0 = tg2 + (co*32 + n)*32 + q*8;
        const float* r1 = r0 + 512;
        #pragma unroll
        for (int j = 0; j < 8; ++j) {
            short h, l, z;
            f2bf_split3(r0[j], &h, &l, &z); b0h[j] = h; b0l[j] = l; b0z[j] = z;
            f2bf_split3(r1[j], &h, &l, &z); b1h[j] = h; b1l[j] = l; b1z[j] = z;
        }
    }
    const short* hhi = (const short*)(ws + WS_HHI_OFF);
    const short* hlo = (const short*)(ws + WS_HLO_OFF);
    const short* hzz = (const short*)(ws + WS_HZZ_OFF);
    uchar* flags = (uchar*)(ws + WS_FLG_OFF);
    const float alp = alpha[0];
    const float bet = beta[0] - 1.0f;
    const float2* ws_meta = (const float2*)(ws + WS_META_OFF);

    #pragma unroll
    for (int it = 0; it < 4; ++it) {
        const int s0 = (((blockIdx.y*4 + wave)*4) + it)*4;

        const int aoff = (s0 + (n >> 2))*128 + (n & 3)*32 + q*8;
        const bf16x8 ah = *(const bf16x8*)(hhi + aoff);
        const bf16x8 al = *(const bf16x8*)(hlo + aoff);
        const bf16x8 az = *(const bf16x8*)(hzz + aoff);

        f32x4 c0 = {0.f, 0.f, 0.f, 0.f};
        f32x4 c1 = {0.f, 0.f, 0.f, 0.f};
        // smallest terms first
        c0 = __builtin_amdgcn_mfma_f32_16x16x32_bf16(az, b0h, c0, 0, 0, 0);
        c0 = __builtin_amdgcn_mfma_f32_16x16x32_bf16(ah, b0z, c0, 0, 0, 0);
        c0 = __builtin_amdgcn_mfma_f32_16x16x32_bf16(al, b0l, c0, 0, 0, 0);
        c0 = __builtin_amdgcn_mfma_f32_16x16x32_bf16(al, b0h, c0, 0, 0, 0);
        c0 = __builtin_amdgcn_mfma_f32_16x16x32_bf16(ah, b0l, c0, 0, 0, 0);
        c0 = __builtin_amdgcn_mfma_f32_16x16x32_bf16(ah, b0h, c0, 0, 0, 0);
        c1 = __builtin_amdgcn_mfma_f32_16x16x32_bf16(az, b1h, c1, 0, 0, 0);
        c1 = __builtin_amdgcn_mfma_f32_16x16x32_bf16(ah, b1z, c1, 0, 0, 0);
        c1 = __builtin_amdgcn_mfma_f32_16x16x32_bf16(al, b1l, c1, 0, 0, 0);
        c1 = __builtin_amdgcn_mfma_f32_16x16x32_bf16(al, b1h, c1, 0, 0, 0);
        c1 = __builtin_amdgcn_mfma_f32_16x16x32_bf16(ah, b1l, c1, 0, 0, 0);
        c1 = __builtin_amdgcn_mfma_f32_16x16x32_bf16(ah, b1h, c1, 0, 0, 0);

        const int site = s0 + q;
        const int b    = site >> 8, hpi = (site >> 4) & 15, wpi = site & 15;
        const int base = ((b*32 + 2*hpi)*32 + 2*wpi)*32;

        float Sx = 0.f, Sy = 0.f, Sxx = 0.f, Sxy = 0.f, Syy = 0.f;
        #pragma unroll
        for (int p = 0; p < 4; ++p) {
            const int idx0 = base + (p >> 1)*1024 + (p & 1)*32 + n;
            const int idx1 = idx0 + 16;
            const float2 pe0 = ((const float2*)pose)[idx0];
            const float2 pe1 = ((const float2*)pose)[idx1];
            const float  a0  = a[idx0];
            const float  a1  = a[idx1];
            float s0n, c0n, s1n, c1n;
            __sincosf(c0[p], &s0n, &c0n);
            __sincosf(c1[p], &s1n, &c1n);
            const float v0x = pe0.x*c0n - pe0.y*s0n;
            const float v0y = pe0.y*c0n + pe0.x*s0n;
            const float v1x = pe1.x*c1n - pe1.y*s1n;
            const float v1y = pe1.y*c1n + pe1.x*s1n;
            const float a0x = a0*v0x, a0y = a0*v0y;
            const float a1x = a1*v1x, a1y = a1*v1y;
            Sx  += a0x + a1x;
            Sy  += a0y + a1y;
            Sxx += a0x*v0x + a1x*v1x;
            Sxy += a0x*v0y + a1x*v1y;
            Syy += a0y*v0y + a1y*v1y;
        }
        #pragma unroll
        for (int m = 1; m <= 8; m <<= 1) {
            Sx  += __shfl_xor(Sx,  m, 64);
            Sy  += __shfl_xor(Sy,  m, 64);
            Sxx += __shfl_xor(Sxx, m, 64);
            Sxy += __shfl_xor(Sxy, m, 64);
            Syy += __shfl_xor(Syy, m, 64);
        }

        float minr2 = 3.4e38f;
        float px, py;
        norm2_guard_m(Sx, Sy, &px, &py, &minr2);
        float qx = px, qy = py;
        #pragma unroll
        for (int it2 = 0; it2 < 3; ++it2) {
            qx = px; qy = py;
            const float mx = Sx + px*Sxx + py*Sxy;
            const float my = Sy + px*Sxy + py*Syy;
            norm2_guard_m(mx, my, &px, &py, &minr2);
        }
        const float2 meta = ws_meta[site];
        const float nd_sum = 0.25f*(meta.x + (px + qx)*Sx + (py + qy)*Sy
                           + px*qx*Sxx + (px*qy + py*qx)*Sxy + py*qy*Syy);
        const float wsum = meta.y;
        const float msk  = (wsum != 0.f) ? 1.f : 0.f;
        const float nd   = nd_sum / (wsum + (1.f - msk)) * msk;
        const float z    = alp*nd + bet;
        const float agr  = msk / (1.f + __expf(-z));
        // margin flag: ||mu|| < 0.05 * Sa
        const int fl = (minr2 < 2.5e-3f*(meta.x*meta.x)) ? 1 : 0;

        if (n == 0) {
            out[OFF_AGR  + site*64  + co]       = agr;
            out[OFF_POSE + site*128 + co*2]     = px;
            out[OFF_POSE + site*128 + co*2 + 1] = py;
            flags[site*64 + co] = (uchar)fl;
        }
    }
}

// ---------------------------------------------------------------------------
// Pass 1.5: compact the 128KB flag array into a worklist. 64 WGs x 256 thr,
// 8 flag bytes per thread; wave-level prefix-sum + ONE atomicAdd per wave
// (<=256 atomics total — no contention).
// ---------------------------------------------------------------------------
__global__ __launch_bounds__(256) void capsC(float* __restrict__ ws)
{
    const int tid  = blockIdx.x*256 + threadIdx.x;
    const int lane = threadIdx.x & 63;
    const unsigned long long v =
        ((const unsigned long long*)(ws + WS_FLG_OFF))[tid];
    unsigned* wl_cnt = (unsigned*)(ws + WS_CNT_OFF);
    int*      wl_lst = (int*)(ws + WS_LST_OFF);

    int cntl = 0;
    #pragma unroll
    for (int j = 0; j < 8; ++j) cntl += (((v >> (8*j)) & 0xFFULL) != 0ULL);

    // inclusive prefix over the wave
    int pref = cntl;
    #pragma unroll
    for (int m = 1; m < 64; m <<= 1) {
        const int u = __shfl_up(pref, m, 64);
        if (lane >= m) pref += u;
    }
    const int total = __shfl(pref, 63, 64);
    int base = 0;
    if (lane == 63 && total > 0) base = (int)atomicAdd(wl_cnt, (unsigned)total);
    base = __shfl(base, 63, 64);

    int o = base + pref - cntl;
    #pragma unroll
    for (int j = 0; j < 8; ++j)
        if ((v >> (8*j)) & 0xFFULL) wl_lst[o++] = tid*8 + j;  // idx == site<<6|co
}

// ---------------------------------------------------------------------------
// Pass 2: exact fixup, worklist-driven + WIDE. 2048 WGs -> 16384 half-waves
// grid-stride the list (~15k entries measured R1) => ~1 entry each, pure
// single-entry latency. Each 32-lane half-wave runs the R13-validated
// routing VERBATIM and overwrites. Uniform early-exit when the list is empty.
// ---------------------------------------------------------------------------
__global__ __launch_bounds__(256) void capsB_fix(
    const float* __restrict__ a, const float* __restrict__ pose,
    const float* __restrict__ tg2, const float* __restrict__ ws,
    const float* __restrict__ alpha, const float* __restrict__ beta,
    float* __restrict__ out)
{
    const unsigned cnt = *(const unsigned*)(ws + WS_CNT_OFF);
    if (cnt == 0) return;

    const int tid  = threadIdx.x;
    const int wave = tid >> 6, lane = tid & 63;
    const int ci   = lane & 31;

    const float alp = alpha[0];
    const float bet = beta[0] - 1.0f;
    const float2* ws_meta = (const float2*)(ws + WS_META_OFF);
    const int* list = (const int*)(ws + WS_LST_OFF);
    const unsigned stride = gridDim.x * 8u;   // half-waves in the grid

    for (unsigned e = (blockIdx.x*4 + wave)*2 + (lane >> 5); e < cnt; e += stride) {
        const int ent = list[e];
        const int s   = ent >> 6;
        const int co  = ent & 63;

        float4 r[8];
        {
            const float4* rp = (const float4*)(tg2 + (co*32 + ci)*32);
            #pragma unroll
            for (int k = 0; k < 8; ++k) r[k] = rp[k];
        }

        const float4* h4 = (const float4*)(ws + s*128);
        float th0 = 0.f, th1 = 0.f, th2 = 0.f, th3 = 0.f;
        #pragma unroll
        for (int k = 0; k < 8; ++k) {
            const float4 rk = r[k];
            const float4 ha = h4[k];
            const float4 hb = h4[8  + k];
            const float4 hc = h4[16 + k];
            const float4 hd = h4[24 + k];
            th0 += rk.x*ha.x + rk.y*ha.y + rk.z*ha.z + rk.w*ha.w;
            th1 += rk.x*hb.x + rk.y*hb.y + rk.z*hb.z + rk.w*hb.w;
            th2 += rk.x*hc.x + rk.y*hc.y + rk.z*hc.z + rk.w*hc.w;
            th3 += rk.x*hd.x + rk.y*hd.y + rk.z*hd.z + rk.w*hd.w;
        }
        const float th[4] = {th0, th1, th2, th3};

        const int b   = s >> 8, hpi = (s >> 4) & 15, wpi = s & 15;
        const int base = ((b*32 + 2*hpi)*32 + 2*wpi)*32 + ci;

        float Sx = 0.f, Sy = 0.f, Sxx = 0.f, Sxy = 0.f, Syy = 0.f;
        #pragma unroll
        for (int p = 0; p < 4; ++p) {
            const int idx = base + (p >> 1)*1024 + (p & 1)*32;
            const float2 pe = ((const float2*)pose)[idx];
            const float  av = a[idx];
            float sn, cs;
            __sincosf(th[p], &sn, &cs);
            const float vx = pe.x*cs - pe.y*sn;
            const float vy = pe.y*cs + pe.x*sn;
            const float ax = av*vx, ay = av*vy;
            Sx += ax; Sy += ay;
            Sxx += ax*vx; Sxy += ax*vy; Syy += ay*vy;
        }
        #pragma unroll
        for (int m = 1; m <= 16; m <<= 1) {
            Sx  += __shfl_xor(Sx,  m, 64);
            Sy  += __shfl_xor(Sy,  m, 64);
            Sxx += __shfl_xor(Sxx, m, 64);
            Sxy += __shfl_xor(Sxy, m, 64);
            Syy += __shfl_xor(Syy, m, 64);
        }

        float px, py;
        norm2_guard(Sx, Sy, &px, &py);
        float qx = px, qy = py;
        #pragma unroll
        for (int it = 0; it < 3; ++it) {
            qx = px; qy = py;
            const float mx = Sx + px*Sxx + py*Sxy;
            const float my = Sy + px*Sxy + py*Syy;
            norm2_guard(mx, my, &px, &py);
        }
        const float2 meta = ws_meta[s];
        const float nd_sum = 0.25f*(meta.x + (px + qx)*Sx + (py + qy)*Sy
                           + px*qx*Sxx + (px*qy + py*qx)*Sxy + py*qy*Syy);
        const float wsum = meta.y;
        const float msk  = (wsum != 0.f) ? 1.f : 0.f;
        const float nd   = nd_sum / (wsum + (1.f - msk)) * msk;
        const float z    = alp*nd + bet;
        const float agr  = msk / (1.f + __expf(-z));

        if ((lane & 31) == 0) {
            out[OFF_AGR  + s*64  + co]       = agr;
            out[OFF_POSE + s*128 + co*2]     = px;
            out[OFF_POSE + s*128 + co*2 + 1] = py;
        }
    }
}

extern "C" void kernel_launch(void* const* d_in, const int* in_sizes, int n_in,
                              void* d_out, int out_size, void* d_ws, size_t ws_size,
                              hipStream_t stream) {
    const float* x     = (const float*)d_in[0];
    const float* a     = (const float*)d_in[1];
    const float* pose  = (const float*)d_in[2];
    const float* alpha = (const float*)d_in[3];
    const float* beta  = (const float*)d_in[4];
    const float* lin_w = (const float*)d_in[5];
    const float* lin_b = (const float*)d_in[6];
    const float* tg1   = (const float*)d_in[7];
    const float* tg2   = (const float*)d_in[8];
    float* out = (float*)d_out;
    float* ws  = (float*)d_ws;   // ~3.3 MB used

    capsA<<<NSITE/4, 256, 0, stream>>>(x, a, pose, tg1, lin_w, lin_b, out, ws);
    capsB_m<<<dim3(64, 32), 256, 0, stream>>>(a, pose, tg2, ws, alpha, beta, out);
    capsC<<<64, 256, 0, stream>>>(ws);
    capsB_fix<<<dim3(2048), 256, 0, stream>>>(a, pose, tg2, ws, alpha, beta, out);
}

// Round 5
// 133.516 us; speedup vs baseline: 4.4535x; 1.0926x over previous
//
#include <hip/hip_runtime.h>
#include <math.h>

#define NSITE 2048

// flat output offsets (floats), reference return order
#define OFF_XOUT 0
#define OFF_AGR  (NSITE*64)                // 131072
#define OFF_POSE (OFF_AGR + NSITE*64)      // 262144
#define OFF_XP   (OFF_POSE + NSITE*128)    // 524288

// ws layout (float indices):
//   [0,262144)        h fp32 [2048][128]           (exact path)
//   [262144,266240)   meta float2 [2048]           (Sa, cnt)
//   [266240,397312)   h_hi bf16 [2048][128] (as shorts)
//   [397312,528384)   h_lo bf16
//   [528384,659456)   h_zz bf16 (3rd split term)
//   [659456,692224)   flags uchar [2048*64]
// total 692224 floats = 2.64 MB
#define WS_META_OFF (NSITE*128)
#define WS_HHI_OFF  266240
#define WS_HLO_OFF  397312
#define WS_HZZ_OFF  528384
#define WS_FLG_OFF  659456

typedef __attribute__((ext_vector_type(8))) short bf16x8;
typedef __attribute__((ext_vector_type(4))) float f32x4;
typedef unsigned char uchar;

__device__ __forceinline__ short f2bf(float f) {
    union { float f; unsigned u; } c; c.f = f;
    const unsigned r = c.u + 0x7FFF + ((c.u >> 16) & 1);   // RNE
    return (short)(r >> 16);
}
__device__ __forceinline__ float bf2f(short h) {
    union { unsigned u; float f; } c; c.u = ((unsigned)(unsigned short)h) << 16;
    return c.f;
}
__device__ __forceinline__ void f2bf_split3(float f, short* hi, short* lo, short* ll) {
    *hi = f2bf(f);
    const float r = f - bf2f(*hi);
    *lo = f2bf(r);
    *ll = f2bf(r - bf2f(*lo));
}

// guarded normalize matching ref semantics: out_c = (mu_c==0) ? 0 : mu_c/||mu||
__device__ __forceinline__ void norm2_guard(float x, float y, float* ox, float* oy) {
    const float n2  = x*x + y*y;
    const float inv = (n2 > 0.f) ? rsqrtf(n2) : 0.f;
    *ox = x*inv; *oy = y*inv;
}
// variant tracking min ||mu||^2 for the margin flag
__device__ __forceinline__ void norm2_guard_m(float x, float y, float* ox, float* oy, float* minr2) {
    const float n2  = x*x + y*y;
    *minr2 = fminf(*minr2, n2);
    const float inv = (n2 > 0.f) ? rsqrtf(n2) : 0.f;
    *ox = x*inv; *oy = y*inv;
}

// ---------------------------------------------------------------------------
// Kernel A: one wave per site (R7-validated pipeline, arithmetic untouched).
// Adds: store h also as a 3-way bf16 split for the MFMA pass A-fragments.
// ---------------------------------------------------------------------------
__global__ __launch_bounds__(256) void capsA(
    const float* __restrict__ x, const float* __restrict__ a,
    const float* __restrict__ pose,
    const float* __restrict__ tg1, const float* __restrict__ lin_w,
    const float* __restrict__ lin_b, float* __restrict__ out,
    float* __restrict__ ws)
{
    const int wave = threadIdx.x >> 6, lane = threadIdx.x & 63;
    const int s  = blockIdx.x*4 + wave;
    const int b  = s >> 8, hp = (s >> 4) & 15, wp = s & 15;
    const int ci = lane & 31, p0 = lane >> 5;           // p0 in {0,1}

    __shared__ float stp[4][4][64];
    __shared__ float xps[4][32];

    const int base = ((b*32 + 2*hp)*32 + 2*wp)*32 + ci;
    const int i0 = base + p0*32;
    const int i1 = base + 1024 + p0*32;
    const float2 pe0 = ((const float2*)pose)[i0];
    const float2 pe1 = ((const float2*)pose)[i1];
    const float  x0  = x[i0], x1 = x[i1];
    const float  a0  = a[i0], a1 = a[i1];

    // pose pooling sum in exact reference order ((p0+p1)+p2)+p3
    const float o0x = __shfl_xor(pe0.x, 32, 64);
    const float o0y = __shfl_xor(pe0.y, 32, 64);
    const float o1x = __shfl_xor(pe1.x, 32, 64);
    const float o1y = __shfl_xor(pe1.y, 32, 64);
    const bool first = (p0 == 0);
    const float A0x = first ? pe0.x : o0x,  A1x = first ? o0x : pe0.x;
    const float A2x = first ? pe1.x : o1x,  A3x = first ? o1x : pe1.x;
    const float A0y = first ? pe0.y : o0y,  A1y = first ? o0y : pe0.y;
    const float A2y = first ? pe1.y : o1y,  A3y = first ? o1y : pe1.y;
    float mx = ((A0x + A1x) + A2x) + A3x;
    float my = ((A0y + A1y) + A2y) + A3y;

    float xm = fmaxf(x0, x1);
    xm = fmaxf(xm, __shfl_xor(xm, 32, 64));
    float sa  = a0 + a1;
    float cnt = (a0 != 0.f ? 1.f : 0.f) + (a1 != 0.f ? 1.f : 0.f);
    sa  += __shfl_xor(sa,  32, 64);
    cnt += __shfl_xor(cnt, 32, 64);
    #pragma unroll
    for (int m = 1; m <= 16; m <<= 1) {
        sa  += __shfl_xor(sa,  m, 64);
        cnt += __shfl_xor(cnt, m, 64);
    }
    if (lane == 0) ((float2*)(ws + WS_META_OFF))[s] = make_float2(sa, cnt);
    if (p0 == 0) {
        out[OFF_XP + s*32 + ci] = xm;
        xps[wave][ci] = xm;
    }

    {
        const float n   = sqrtf(mx*mx + my*my);
        const float den = n + (n == 0.f ? 1.f : 0.f);
        mx /= den; my /= den;
    }
    {
        const float ww_ = (float)p0 - 0.5f;
        const float t0x = -0.5f*mx + my*ww_;
        const float t0y =  0.5f*my + mx*ww_;
        const float t1x =  0.5f*mx + my*ww_;
        const float t1y = -0.5f*my + mx*ww_;
        ((float2*)stp[wave][p0    ])[ci] = make_float2(t0x, t0y);
        ((float2*)stp[wave][p0 + 2])[ci] = make_float2(t1x, t1y);
    }
    __syncthreads();

    {
        const float4* w4 = (const float4*)(tg1 + ci*64);
        const float4* r0 = (const float4*)stp[wave][p0];
        const float4* r1 = (const float4*)stp[wave][p0 + 2];
        float h0 = 0.f, h1 = 0.f;
        #pragma unroll
        for (int k = 0; k < 16; ++k) {
            const float4 wv = w4[k], u = r0[k], v = r1[k];
            h0 += wv.x*u.x + wv.y*u.y + wv.z*u.z + wv.w*u.w;
            h1 += wv.x*v.x + wv.y*v.y + wv.z*v.z + wv.w*v.w;
        }
        ws[s*128 + p0*32 + ci]       = h0;
        ws[s*128 + (p0 + 2)*32 + ci] = h1;
        // bf16 3-way split for the MFMA pass
        short* hhi = (short*)(ws + WS_HHI_OFF);
        short* hlo = (short*)(ws + WS_HLO_OFF);
        short* hzz = (short*)(ws + WS_HZZ_OFF);
        short h0h, h0l, h0z, h1h, h1l, h1z;
        f2bf_split3(h0, &h0h, &h0l, &h0z);
        f2bf_split3(h1, &h1h, &h1l, &h1z);
        const int e0 = s*128 + p0*32 + ci;
        const int e1 = s*128 + (p0 + 2)*32 + ci;
        hhi[e0] = h0h; hhi[e1] = h1h;
        hlo[e0] = h0l; hlo[e1] = h1l;
        hzz[e0] = h0z; hzz[e1] = h1z;
    }

    {
        float acc = lin_b[lane];
        const float4* lw = (const float4*)(lin_w + lane*32);
        const float4* xv = (const float4*)xps[wave];
        #pragma unroll
        for (int k = 0; k < 8; ++k) {
            const float4 wv = lw[k], u = xv[k];
            acc += wv.x*u.x + wv.y*u.y + wv.z*u.z + wv.w*u.w;
        }
        out[OFF_XOUT + s*64 + lane] = acc;
    }
}

// ---------------------------------------------------------------------------
// Pass 1: MFMA theta (A 3-way x B 3-way, 6 terms kept per half -> dtheta
// ~3e-8, vs 5e-6 in R14 which missed threshold by 0.3%) + moment routing for
// ALL pairs, tracking min ||mu||^2; flags pairs with ||mu|| < 0.05*Sa for
// exact recomputation (R14 evidence: this flag catches ALL bistable pairs —
// max unflagged error was linear-amplification 0.0996, no 0.164 flips).
// Wave tile: M=16 (4 sites x 4 p) x N=32 (one co), K=32.
// ---------------------------------------------------------------------------
__global__ __launch_bounds__(256) void capsB_m(
    const float* __restrict__ a, const float* __restrict__ pose,
    const float* __restrict__ tg2, float* __restrict__ ws,
    const float* __restrict__ alpha, const float* __restrict__ beta,
    float* __restrict__ out)
{
    const int co   = blockIdx.x;
    const int tid  = threadIdx.x;
    const int wave = tid >> 6, lane = tid & 63;
    const int q    = lane >> 4;
    const int n    = lane & 15;

    // B fragments, 3-way split (once per wave)
    bf16x8 b0h, b0l, b0z, b1h, b1l, b1z;
    {
        const float* r0 = tg2 + (co*32 + n)*32 + q*8;
        const float* r1 = r0 + 512;
        #pragma unroll
        for (int j = 0; j < 8; ++j) {
            short h, l, z;
            f2bf_split3(r0[j], &h, &l, &z); b0h[j] = h; b0l[j] = l; b0z[j] = z;
            f2bf_split3(r1[j], &h, &l, &z); b1h[j] = h; b1l[j] = l; b1z[j] = z;
        }
    }
    const short* hhi = (const short*)(ws + WS_HHI_OFF);
    const short* hlo = (const short*)(ws + WS_HLO_OFF);
    const short* hzz = (const short*)(ws + WS_HZZ_OFF);
    uchar* flags = (uchar*)(ws + WS_FLG_OFF);
    const float alp = alpha[0];
    const float bet = beta[0] - 1.0f;
    const float2* ws_meta = (const float2*)(ws + WS_META_OFF);

    #pragma unroll
    for (int it = 0; it < 4; ++it) {
        const int s0 = (((blockIdx.y*4 + wave)*4) + it)*4;

        const int aoff = (s0 + (n >> 2))*128 + (n & 3)*32 + q*8;
        const bf16x8 ah = *(const bf16x8*)(hhi + aoff);
        const bf16x8 al = *(const bf16x8*)(hlo + aoff);
        const bf16x8 az = *(const bf16x8*)(hzz + aoff);

        f32x4 c0 = {0.f, 0.f, 0.f, 0.f};
        f32x4 c1 = {0.f, 0.f, 0.f, 0.f};
        // smallest terms first
        c0 = __builtin_amdgcn_mfma_f32_16x16x32_bf16(az, b0h, c0, 0, 0, 0);
        c0 = __builtin_amdgcn_mfma_f32_16x16x32_bf16(ah, b0z, c0, 0, 0, 0);
        c0 = __builtin_amdgcn_mfma_f32_16x16x32_bf16(al, b0l, c0, 0, 0, 0);
        c0 = __builtin_amdgcn_mfma_f32_16x16x32_bf16(al, b0h, c0, 0, 0, 0);
        c0 = __builtin_amdgcn_mfma_f32_16x16x32_bf16(ah, b0l, c0, 0, 0, 0);
        c0 = __builtin_amdgcn_mfma_f32_16x16x32_bf16(ah, b0h, c0, 0, 0, 0);
        c1 = __builtin_amdgcn_mfma_f32_16x16x32_bf16(az, b1h, c1, 0, 0, 0);
        c1 = __builtin_amdgcn_mfma_f32_16x16x32_bf16(ah, b1z, c1, 0, 0, 0);
        c1 = __builtin_amdgcn_mfma_f32_16x16x32_bf16(al, b1l, c1, 0, 0, 0);
        c1 = __builtin_amdgcn_mfma_f32_16x16x32_bf16(al, b1h, c1, 0, 0, 0);
        c1 = __builtin_amdgcn_mfma_f32_16x16x32_bf16(ah, b1l, c1, 0, 0, 0);
        c1 = __builtin_amdgcn_mfma_f32_16x16x32_bf16(ah, b1h, c1, 0, 0, 0);

        const int site = s0 + q;
        const int b    = site >> 8, hpi = (site >> 4) & 15, wpi = site & 15;
        const int base = ((b*32 + 2*hpi)*32 + 2*wpi)*32;

        float Sx = 0.f, Sy = 0.f, Sxx = 0.f, Sxy = 0.f, Syy = 0.f;
        #pragma unroll
        for (int p = 0; p < 4; ++p) {
            const int idx0 = base + (p >> 1)*1024 + (p & 1)*32 + n;
            const int idx1 = idx0 + 16;
            const float2 pe0 = ((const float2*)pose)[idx0];
            const float2 pe1 = ((const float2*)pose)[idx1];
            const float  a0  = a[idx0];
            const float  a1  = a[idx1];
            float s0n, c0n, s1n, c1n;
            __sincosf(c0[p], &s0n, &c0n);
            __sincosf(c1[p], &s1n, &c1n);
            const float v0x = pe0.x*c0n - pe0.y*s0n;
            const float v0y = pe0.y*c0n + pe0.x*s0n;
            const float v1x = pe1.x*c1n - pe1.y*s1n;
            const float v1y = pe1.y*c1n + pe1.x*s1n;
            const float a0x = a0*v0x, a0y = a0*v0y;
            const float a1x = a1*v1x, a1y = a1*v1y;
            Sx  += a0x + a1x;
            Sy  += a0y + a1y;
            Sxx += a0x*v0x + a1x*v1x;
            Sxy += a0x*v0y + a1x*v1y;
            Syy += a0y*v0y + a1y*v1y;
        }
        #pragma unroll
        for (int m = 1; m <= 8; m <<= 1) {
            Sx  += __shfl_xor(Sx,  m, 64);
            Sy  += __shfl_xor(Sy,  m, 64);
            Sxx += __shfl_xor(Sxx, m, 64);
            Sxy += __shfl_xor(Sxy, m, 64);
            Syy += __shfl_xor(Syy, m, 64);
        }

        float minr2 = 3.4e38f;
        float px, py;
        norm2_guard_m(Sx, Sy, &px, &py, &minr2);
        float qx = px, qy = py;
        #pragma unroll
        for (int it2 = 0; it2 < 3; ++it2) {
            qx = px; qy = py;
            const float mx = Sx + px*Sxx + py*Sxy;
            const float my = Sy + px*Sxy + py*Syy;
            norm2_guard_m(mx, my, &px, &py, &minr2);
        }
        const float2 meta = ws_meta[site];
        const float nd_sum = 0.25f*(meta.x + (px + qx)*Sx + (py + qy)*Sy
                           + px*qx*Sxx + (px*qy + py*qx)*Sxy + py*qy*Syy);
        const float wsum = meta.y;
        const float msk  = (wsum != 0.f) ? 1.f : 0.f;
        const float nd   = nd_sum / (wsum + (1.f - msk)) * msk;
        const float z    = alp*nd + bet;
        const float agr  = msk / (1.f + __expf(-z));
        // margin flag: ||mu|| < 0.05 * Sa
        const int fl = (minr2 < 2.5e-3f*(meta.x*meta.x)) ? 1 : 0;

        if (n == 0) {
            out[OFF_AGR  + site*64  + co]       = agr;
            out[OFF_POSE + site*128 + co*2]     = px;
            out[OFF_POSE + site*128 + co*2 + 1] = py;
            flags[site*64 + co] = (uchar)fl;
        }
    }
}

// ---------------------------------------------------------------------------
// Pass 2: exact fixup. Grid (8, 2048): one site per wave; early-exit unless
// some lane's (site,co) is flagged; otherwise run the R13-validated routing
// VERBATIM (bit-identical to the 0.0039 pass) and overwrite.
// ---------------------------------------------------------------------------
__global__ __launch_bounds__(256) void capsB_fix(
    const float* __restrict__ a, const float* __restrict__ pose,
    const float* __restrict__ tg2, const float* __restrict__ ws,
    const float* __restrict__ alpha, const float* __restrict__ beta,
    float* __restrict__ out)
{
    const int g    = blockIdx.x;
    const int s    = blockIdx.y;            // one site per wave
    const int tid  = threadIdx.x;
    const int wave = tid >> 6, lane = tid & 63;
    const int co   = g*8 + wave*2 + (lane >> 5);
    const int ci   = lane & 31;

    const uchar* flags = (const uchar*)(ws + WS_FLG_OFF);
    const bool need = flags[s*64 + co] != 0;
    if (__ballot(need) == 0ULL) return;

    float4 r[8];
    {
        const float4* rp = (const float4*)(tg2 + (co*32 + ci)*32);
        #pragma unroll
        for (int k = 0; k < 8; ++k) r[k] = rp[k];
    }
    const float alp = alpha[0];
    const float bet = beta[0] - 1.0f;
    const float2* ws_meta = (const float2*)(ws + WS_META_OFF);

    const float4* h4 = (const float4*)(ws + s*128);
    float th0 = 0.f, th1 = 0.f, th2 = 0.f, th3 = 0.f;
    #pragma unroll
    for (int k = 0; k < 8; ++k) {
        const float4 rk = r[k];
        const float4 ha = h4[k];
        const float4 hb = h4[8  + k];
        const float4 hc = h4[16 + k];
        const float4 hd = h4[24 + k];
        th0 += rk.x*ha.x + rk.y*ha.y + rk.z*ha.z + rk.w*ha.w;
        th1 += rk.x*hb.x + rk.y*hb.y + rk.z*hb.z + rk.w*hb.w;
        th2 += rk.x*hc.x + rk.y*hc.y + rk.z*hc.z + rk.w*hc.w;
        th3 += rk.x*hd.x + rk.y*hd.y + rk.z*hd.z + rk.w*hd.w;
    }
    const float th[4] = {th0, th1, th2, th3};

    const int b   = s >> 8, hpi = (s >> 4) & 15, wpi = s & 15;
    const int base = ((b*32 + 2*hpi)*32 + 2*wpi)*32 + ci;

    float Sx = 0.f, Sy = 0.f, Sxx = 0.f, Sxy = 0.f, Syy = 0.f;
    #pragma unroll
    for (int p = 0; p < 4; ++p) {
        const int idx = base + (p >> 1)*1024 + (p & 1)*32;
        const float2 pe = ((const float2*)pose)[idx];
        const float  av = a[idx];
        float sn, cs;
        __sincosf(th[p], &sn, &cs);
        const float vx = pe.x*cs - pe.y*sn;
        const float vy = pe.y*cs + pe.x*sn;
        const float ax = av*vx, ay = av*vy;
        Sx += ax; Sy += ay;
        Sxx += ax*vx; Sxy += ax*vy; Syy += ay*vy;
    }
    #pragma unroll
    for (int m = 1; m <= 16; m <<= 1) {
        Sx  += __shfl_xor(Sx,  m, 64);
        Sy  += __shfl_xor(Sy,  m, 64);
        Sxx += __shfl_xor(Sxx, m, 64);
        Sxy += __shfl_xor(Sxy, m, 64);
        Syy += __shfl_xor(Syy, m, 64);
    }

    float px, py;
    norm2_guard(Sx, Sy, &px, &py);
    float qx = px, qy = py;
    #pragma unroll
    for (int it = 0; it < 3; ++it) {
        qx = px; qy = py;
        const float mx = Sx + px*Sxx + py*Sxy;
        const float my = Sy + px*Sxy + py*Syy;
        norm2_guard(mx, my, &px, &py);
    }
    const float2 meta = ws_meta[s];
    const float nd_sum = 0.25f*(meta.x + (px + qx)*Sx + (py + qy)*Sy
                       + px*qx*Sxx + (px*qy + py*qx)*Sxy + py*qy*Syy);
    const float wsum = meta.y;
    const float msk  = (wsum != 0.f) ? 1.f : 0.f;
    const float nd   = nd_sum / (wsum + (1.f - msk)) * msk;
    const float z    = alp*nd + bet;
    const float agr  = msk / (1.f + __expf(-z));

    if ((lane & 31) == 0) {
        out[OFF_AGR  + s*64  + co]       = agr;
        out[OFF_POSE + s*128 + co*2]     = px;
        out[OFF_POSE + s*128 + co*2 + 1] = py;
    }
}

extern "C" void kernel_launch(void* const* d_in, const int* in_sizes, int n_in,
                              void* d_out, int out_size, void* d_ws, size_t ws_size,
                              hipStream_t stream) {
    const float* x     = (const float*)d_in[0];
    const float* a     = (const float*)d_in[1];
    const float* pose  = (const float*)d_in[2];
    const float* alpha = (const float*)d_in[3];
    const float* beta  = (const float*)d_in[4];
    const float* lin_w = (const float*)d_in[5];
    const float* lin_b = (const float*)d_in[6];
    const float* tg1   = (const float*)d_in[7];
    const float* tg2   = (const float*)d_in[8];
    float* out = (float*)d_out;
    float* ws  = (float*)d_ws;   // 2.64 MB used

    capsA<<<NSITE/4, 256, 0, stream>>>(x, a, pose, tg1, lin_w, lin_b, out, ws);
    capsB_m<<<dim3(64, 32), 256, 0, stream>>>(a, pose, tg2, ws, alpha, beta, out);
    capsB_fix<<<dim3(8, NSITE), 256, 0, stream>>>(a, pose, tg2, ws, alpha, beta, out);
}